// Round 3
// baseline (106.087 us; speedup 1.0000x reference)
//
#include <hip/hip_runtime.h>
#include <hip/hip_bf16.h>

#define B_N 2048
#define D_V 8
#define F_D 256
#define TILE 128
#define BC 64
#define LSTRB 272    // fp8 LDS row stride in bytes (256 + 16 pad breaks pow2 banking)
#define NTILES 136   // 16*17/2 upper-triangle 128x128 tiles

typedef __attribute__((ext_vector_type(8))) short short8;
typedef __attribute__((ext_vector_type(4))) float floatx4;
typedef __attribute__((ext_vector_type(8))) int int8v;

__device__ inline unsigned short f2bf(float f) {
    __hip_bfloat16 h = __float2bfloat16(f);
    return *reinterpret_cast<unsigned short*>(&h);
}

__device__ inline float wave_reduce_sum(float v) {
    #pragma unroll
    for (int off = 1; off < 64; off <<= 1)
        v += __shfl_xor(v, off, 64);
    return v;
}

// ---------------------------------------------------------------------------
// Kernel 1: normalize each (b,d) row; emit bf16 zn (for pos) AND fp8-e4m3 zn8
// (for neg), both in [d][b][f] layout. One wave per row. Also zero-inits
// ns8[8][2048] and the neg completion counter.
// ---------------------------------------------------------------------------
__global__ void norm_kernel(const float* __restrict__ z,
                            unsigned short* __restrict__ zn,
                            unsigned char* __restrict__ zn8,
                            float* __restrict__ ns8,
                            unsigned int* __restrict__ counter) {
    int gid = blockIdx.x * blockDim.x + threadIdx.x;
    if (gid < D_V * B_N) ns8[gid] = 0.0f;
    if (gid == 0) *counter = 0u;
    int wave = gid >> 6;  // row = b*8+d
    int lane = threadIdx.x & 63;
    const float4* zp = (const float4*)(z + (size_t)wave * F_D);
    float4 v = zp[lane];
    float ss = v.x * v.x + v.y * v.y + v.z * v.z + v.w * v.w;
    ss = wave_reduce_sum(ss);
    float inv = 1.0f / fmaxf(sqrtf(ss), 1e-12f);
    float x0 = v.x * inv, x1 = v.y * inv, x2 = v.z * inv, x3 = v.w * inv;
    int b = wave >> 3, d = wave & 7;
    size_t rowoff = (size_t)d * (B_N * F_D) + (size_t)b * F_D;
    ushort4 o;
    o.x = f2bf(x0); o.y = f2bf(x1); o.z = f2bf(x2); o.w = f2bf(x3);
    *(ushort4*)(zn + rowoff + lane * 4) = o;
    int packed = 0;
    packed = __builtin_amdgcn_cvt_pk_fp8_f32(x0, x1, packed, false);
    packed = __builtin_amdgcn_cvt_pk_fp8_f32(x2, x3, packed, true);
    *(int*)(zn8 + rowoff + lane * 4) = packed;
}

// ---------------------------------------------------------------------------
// Kernel 2: pos[b] = sum_{d!=e} exp(2*dot(zn[b,d], zn[b,e]))  (bf16 MFMA)
// One wave handles 2 samples: 16 rows = [s0 views 0..7 | s1 views 0..7].
// ---------------------------------------------------------------------------
__global__ void pos_kernel(const unsigned short* __restrict__ zn,
                           float* __restrict__ pos) {
    int gw = (blockIdx.x * blockDim.x + threadIdx.x) >> 6;
    int lane = threadIdx.x & 63;
    int q = lane >> 4, li = lane & 15;
    int s0 = gw * 2;
    int b = s0 + (li >> 3), d = li & 7;
    const unsigned short* rowp = zn + (size_t)d * (B_N * F_D) + (size_t)b * F_D;
    short8 a[8];
    #pragma unroll
    for (int kk = 0; kk < 8; kk++)
        a[kk] = *(const short8*)(rowp + kk * 32 + q * 8);
    floatx4 acc = {0.f, 0.f, 0.f, 0.f};
    #pragma unroll
    for (int kk = 0; kk < 8; kk++)
        acc = __builtin_amdgcn_mfma_f32_16x16x32_bf16(a[kk], a[kk], acc, 0, 0, 0);
    float p0 = 0.f, p1 = 0.f;
    #pragma unroll
    for (int r = 0; r < 4; r++) {
        int row = q * 4 + r, col = li;
        bool same_sample = (row >> 3) == (col >> 3);
        if (same_sample && row != col) {
            float e = __expf(2.0f * acc[r]);
            if (row < 8) p0 += e; else p1 += e;
        }
    }
    p0 = wave_reduce_sum(p0);
    p1 = wave_reduce_sum(p1);
    if (lane == 0) { pos[s0] = p0; pos[s0 + 1] = p1; }
}

// ---------------------------------------------------------------------------
// Kernel 3: per view d, upper-triangle 128x128 tiles (i<=j) of exp(2*Z Z^T):
// row-sums -> ns8[d][i-strip]; off-diag tiles also col-sums -> ns8[d][j-strip].
// MX-fp8 MFMA (16x16x128, unit scales): K=256 in 2 instrs, A resident in regs.
// Last block to finish computes the final loss (ticket counter).
// ---------------------------------------------------------------------------
__global__ __launch_bounds__(128, 2)
void neg_kernel(const unsigned char* __restrict__ zn8,
                const float* __restrict__ pos,
                float* __restrict__ ns8,
                unsigned int* __restrict__ counter,
                float* __restrict__ out) {
    __shared__ __align__(16) unsigned char Bs[BC * LSTRB];  // 17 KB
    __shared__ float csred[2][TILE];
    __shared__ unsigned int sticket;
    const int d = blockIdx.y;
    int trem = blockIdx.x;            // 0..135 -> (i,j), i<=j
    int i = 0;
    while (trem >= 16 - i) { trem -= 16 - i; ++i; }
    const int j = i + trem;
    const bool diag = (i == j);
    const unsigned char* Z = zn8 + (size_t)d * (B_N * F_D);
    int tid = threadIdx.x, w = tid >> 6, lane = tid & 63;
    int q = lane >> 4, li = lane & 15;
    int r0 = i * TILE + w * 64;       // this wave's 64 A-rows (4 MFMA row-sets)

    // A fragments: f8f6f4 16x16x128 layout: row=lane&15, k=(lane>>4)*32 + byte
    int8v a[4][2];
    #pragma unroll
    for (int s = 0; s < 4; s++) {
        #pragma unroll
        for (int ki = 0; ki < 2; ki++) {
            const int4* p = (const int4*)(Z + (size_t)(r0 + s * 16 + li) * F_D + ki * 128 + q * 32);
            int4 lo = p[0], hi = p[1];
            int8v t;
            t[0] = lo.x; t[1] = lo.y; t[2] = lo.z; t[3] = lo.w;
            t[4] = hi.x; t[5] = hi.y; t[6] = hi.z; t[7] = hi.w;
            a[s][ki] = t;
        }
    }

    float rs[4][4];
    #pragma unroll
    for (int s = 0; s < 4; s++)
        #pragma unroll
        for (int r = 0; r < 4; r++) rs[s][r] = 0.f;
    float cacc[2] = {0.f, 0.f};

    for (int stage = 0; stage < 2; ++stage) {
        int c0 = j * TILE + stage * BC;
        __syncthreads();
        // stage 64 rows x 256 B: 1024 16B-chunks, 8 per thread
        #pragma unroll
        for (int it = 0; it < 8; ++it) {
            int idx = it * 128 + tid;
            int row = idx >> 4, kc = idx & 15;
            *(int4*)(&Bs[row * LSTRB + kc * 16]) =
                *(const int4*)(Z + (size_t)(c0 + row) * F_D + kc * 16);
        }
        __syncthreads();
        #pragma unroll
        for (int ct = 0; ct < 4; ++ct) {
            floatx4 acc[4];
            #pragma unroll
            for (int s = 0; s < 4; s++) acc[s] = (floatx4){0.f, 0.f, 0.f, 0.f};
            #pragma unroll
            for (int ki = 0; ki < 2; ki++) {
                const unsigned char* bp = &Bs[(ct * 16 + li) * LSTRB + ki * 128 + q * 32];
                int4 lo = *(const int4*)bp;
                int4 hi = *(const int4*)(bp + 16);
                int8v bv;
                bv[0] = lo.x; bv[1] = lo.y; bv[2] = lo.z; bv[3] = lo.w;
                bv[4] = hi.x; bv[5] = hi.y; bv[6] = hi.z; bv[7] = hi.w;
                #pragma unroll
                for (int s = 0; s < 4; s++)
                    acc[s] = __builtin_amdgcn_mfma_scale_f32_16x16x128_f8f6f4(
                        a[s][ki], bv, acc[s], 0, 0,           // cbsz=fp8, blgp=fp8
                        0, 0x7f7f7f7f, 0, 0x7f7f7f7f);        // unit e8m0 scales
            }
            int gcol = c0 + ct * 16 + li;
            float csum = 0.f;
            #pragma unroll
            for (int s = 0; s < 4; s++) {
                #pragma unroll
                for (int r = 0; r < 4; r++) {
                    float e = __expf(2.0f * acc[s][r]);
                    int grow = r0 + s * 16 + q * 4 + r;
                    e = (diag && grow == gcol) ? 0.f : e;
                    rs[s][r] += e;
                    csum += e;
                }
            }
            csum += __shfl_xor(csum, 16, 64);
            csum += __shfl_xor(csum, 32, 64);
            if (q == ct) cacc[stage] += csum;   // lane holds col ct*16+li == lane
        }
    }

    // row sums: reduce across the 16 column-lanes
    #pragma unroll
    for (int off = 1; off < 16; off <<= 1)
        #pragma unroll
        for (int s = 0; s < 4; s++)
            #pragma unroll
            for (int r = 0; r < 4; r++)
                rs[s][r] += __shfl_xor(rs[s][r], off, 64);
    if (li == 0) {
        #pragma unroll
        for (int s = 0; s < 4; s++)
            #pragma unroll
            for (int r = 0; r < 4; r++)
                atomicAdd(&ns8[d * B_N + r0 + s * 16 + q * 4 + r], rs[s][r]);
    }

    // col sums: combine 2 waves via LDS, one atomic per column
    csred[w][lane] = cacc[0];
    csred[w][64 + lane] = cacc[1];
    __syncthreads();
    if (!diag && tid < TILE) {
        float v = csred[0][tid] + csred[1][tid];
        atomicAdd(&ns8[d * B_N + j * TILE + tid], v);
    }

    // ---- fused final: last block computes the loss ----
    __syncthreads();
    if (tid == 0) { __threadfence(); sticket = atomicAdd(counter, 1u); }
    __syncthreads();
    if (sticket == (unsigned)(NTILES * D_V - 1)) {
        __threadfence();
        float vals[16];
        float lmax = -1e30f;
        #pragma unroll
        for (int ii = 0; ii < 16; ii++) {
            int idx = ii * 128 + tid;
            float nsum = 0.f;
            #pragma unroll
            for (int dd = 0; dd < D_V; dd++) nsum += ns8[dd * B_N + idx];
            float p = pos[idx];
            float l = p / (p + nsum * (1.0f / (float)(B_N - 1)));
            vals[ii] = l;
            lmax = fmaxf(lmax, l);
        }
        float* red = &csred[0][0];
        red[tid] = lmax; __syncthreads();
        for (int s2 = 64; s2 > 0; s2 >>= 1) {
            if (tid < s2) red[tid] = fmaxf(red[tid], red[tid + s2]);
            __syncthreads();
        }
        float m = red[0]; __syncthreads();
        float se = 0.f, sl = 0.f;
        #pragma unroll
        for (int ii = 0; ii < 16; ii++) { se += expf(vals[ii] - m); sl += vals[ii]; }
        red[tid] = se; __syncthreads();
        for (int s2 = 64; s2 > 0; s2 >>= 1) {
            if (tid < s2) red[tid] += red[tid + s2];
            __syncthreads();
        }
        float S = red[0]; __syncthreads();
        red[tid] = sl; __syncthreads();
        for (int s2 = 64; s2 > 0; s2 >>= 1) {
            if (tid < s2) red[tid] += red[tid + s2];
            __syncthreads();
        }
        if (tid == 0) out[0] = m + logf(S) - red[0] * (1.0f / (float)B_N);
    }
}

extern "C" void kernel_launch(void* const* d_in, const int* in_sizes, int n_in,
                              void* d_out, int out_size, void* d_ws, size_t ws_size,
                              hipStream_t stream) {
    const float* z = (const float*)d_in[0];
    float* out = (float*)d_out;
    unsigned short* zn = (unsigned short*)d_ws;                          // 8 MB bf16
    unsigned char* zn8 = (unsigned char*)d_ws + (size_t)D_V * B_N * F_D * 2;  // 4 MB fp8
    float* ns8 = (float*)(zn8 + (size_t)D_V * B_N * F_D);                // 64 KB
    float* pos = ns8 + D_V * B_N;                                        // 8 KB
    unsigned int* counter = (unsigned int*)(pos + B_N);                  // 4 B

    norm_kernel<<<dim3(4096), 256, 0, stream>>>(z, zn, zn8, ns8, counter);
    pos_kernel<<<dim3(256), 256, 0, stream>>>(zn, pos);
    neg_kernel<<<dim3(NTILES, D_V), 128, 0, stream>>>(zn8, pos, ns8, counter, out);
}